// Round 2
// baseline (623.212 us; speedup 1.0000x reference)
//
#include <hip/hip_runtime.h>
#include <hip/hip_bf16.h>

typedef __attribute__((ext_vector_type(8))) short bf16x8;
typedef __attribute__((ext_vector_type(4))) float f32x4;
typedef unsigned int u32;
typedef unsigned short u16;

// ---- workspace layout (float indices) ----
#define WS_G1     0         // 512x512 compact
#define WS_G2     262144    // 512x512 compact
#define WS_COLSUM 524288    // 512
#define WS_VSQ    524800
#define WS_GATES  524801    // 3
#define WS_TR1    524804
#define WS_TR2    524805
#define WS_PART   524808    // 26 jobs x 32 chunks x 16384 floats (frag layout)

// ---- output layout (float indices) ----
#define OUT_LOSS 33554432
#define OUT_W    33554433
#define OUT_S    33816577

__device__ inline u32 pkbf2(float a, float b) {
    __hip_bfloat162 h2 = __float22bfloat162_rn(make_float2(a, b));
    u32 r;
    __builtin_memcpy(&r, &h2, 4);
    return r;
}

__device__ inline void jobdec(int j, int& isG2, int& rt, int& ct) {
    if (j >= 10) { isG2 = 1; rt = (j - 10) >> 2; ct = (j - 10) & 3; }
    else {
        isG2 = 0;
        if (j < 4)      { rt = 0; ct = j; }
        else if (j < 7) { rt = 1; ct = j - 3; }
        else if (j < 9) { rt = 2; ct = j - 5; }
        else            { rt = 3; ct = 3; }
    }
}

// =====================================================================
// KG: Gram partials. G1 = k^T k (10 upper-tri 128x128 tiles),
// G2 = v^T k (16 tiles). 32 b-chunks of 2048. 832 blocks.
// bx = j*32 + c  ->  chunk c pinned to XCD c%8.
// Also: colsum(k) (G2 jobs with rt==0), sum(v^2) (G2 jobs with ct==0).
// =====================================================================
__global__ __launch_bounds__(256, 3)
void kg_gram(const float* __restrict__ kmat, const float* __restrict__ vmat,
             float* __restrict__ ws) {
    __shared__ u16 sm[18432];          // As 128x72, Bs 128x72
    u16* As = sm;
    u16* Bs = sm + 9216;

    const int tid = threadIdx.x;
    const int bx = blockIdx.x;
    const int c = bx & 31;
    const int j = bx >> 5;
    int isG2, rt, ct;
    jobdec(j, isG2, rt, ct);
    const float* Asrc = (isG2 ? vmat : kmat) + rt * 128;
    const float* Bsrc = kmat + ct * 128;
    const bool doCS = isG2 && (rt == 0);
    const bool doVS = isG2 && (ct == 0);
    const long b0 = (long)c * 2048;

    const int wv = tid >> 6, lane = tid & 63;
    const int wm = wv & 1, wn = wv >> 1;
    const int col = lane & 15, kg = lane >> 4;
    const int bcol = (tid & 63) * 2;        // column pair within 128-stripe
    const int bq = wv * 16;                 // b sub-block within 64

    f32x4 acc[4][4] = {};
    float cs0 = 0.f, cs1 = 0.f, vs = 0.f;

    float2 aR[16], bR[16];
    {
        const float* ga = Asrc + (b0 + bq) * 512 + bcol;
        const float* gb = Bsrc + (b0 + bq) * 512 + bcol;
#pragma unroll
        for (int i = 0; i < 16; ++i) {
            aR[i] = *(const float2*)(ga + (long)i * 512);
            bR[i] = *(const float2*)(gb + (long)i * 512);
        }
    }

    for (int it = 0; it < 32; ++it) {
        __syncthreads();
        if (doVS) {
#pragma unroll
            for (int i = 0; i < 16; ++i) vs += aR[i].x * aR[i].x + aR[i].y * aR[i].y;
        }
        if (doCS) {
#pragma unroll
            for (int i = 0; i < 16; ++i) { cs0 += bR[i].x; cs1 += bR[i].y; }
        }
        *(uint4*)&As[bcol * 72 + bq] = make_uint4(
            pkbf2(aR[0].x, aR[1].x), pkbf2(aR[2].x, aR[3].x),
            pkbf2(aR[4].x, aR[5].x), pkbf2(aR[6].x, aR[7].x));
        *(uint4*)&As[bcol * 72 + bq + 8] = make_uint4(
            pkbf2(aR[8].x, aR[9].x), pkbf2(aR[10].x, aR[11].x),
            pkbf2(aR[12].x, aR[13].x), pkbf2(aR[14].x, aR[15].x));
        *(uint4*)&As[(bcol + 1) * 72 + bq] = make_uint4(
            pkbf2(aR[0].y, aR[1].y), pkbf2(aR[2].y, aR[3].y),
            pkbf2(aR[4].y, aR[5].y), pkbf2(aR[6].y, aR[7].y));
        *(uint4*)&As[(bcol + 1) * 72 + bq + 8] = make_uint4(
            pkbf2(aR[8].y, aR[9].y), pkbf2(aR[10].y, aR[11].y),
            pkbf2(aR[12].y, aR[13].y), pkbf2(aR[14].y, aR[15].y));
        *(uint4*)&Bs[bcol * 72 + bq] = make_uint4(
            pkbf2(bR[0].x, bR[1].x), pkbf2(bR[2].x, bR[3].x),
            pkbf2(bR[4].x, bR[5].x), pkbf2(bR[6].x, bR[7].x));
        *(uint4*)&Bs[bcol * 72 + bq + 8] = make_uint4(
            pkbf2(bR[8].x, bR[9].x), pkbf2(bR[10].x, bR[11].x),
            pkbf2(bR[12].x, bR[13].x), pkbf2(bR[14].x, bR[15].x));
        *(uint4*)&Bs[(bcol + 1) * 72 + bq] = make_uint4(
            pkbf2(bR[0].y, bR[1].y), pkbf2(bR[2].y, bR[3].y),
            pkbf2(bR[4].y, bR[5].y), pkbf2(bR[6].y, bR[7].y));
        *(uint4*)&Bs[(bcol + 1) * 72 + bq + 8] = make_uint4(
            pkbf2(bR[8].y, bR[9].y), pkbf2(bR[10].y, bR[11].y),
            pkbf2(bR[12].y, bR[13].y), pkbf2(bR[14].y, bR[15].y));
        __syncthreads();
        if (it < 31) {
            const float* ga = Asrc + (b0 + (it + 1) * 64 + bq) * 512 + bcol;
            const float* gb = Bsrc + (b0 + (it + 1) * 64 + bq) * 512 + bcol;
#pragma unroll
            for (int i = 0; i < 16; ++i) {
                aR[i] = *(const float2*)(ga + (long)i * 512);
                bR[i] = *(const float2*)(gb + (long)i * 512);
            }
        }
#pragma unroll
        for (int kk = 0; kk < 2; ++kk) {
            bf16x8 af[4], bfr[4];
#pragma unroll
            for (int i = 0; i < 4; ++i)
                af[i] = *(const bf16x8*)&As[(wm * 64 + i * 16 + col) * 72 + kk * 32 + kg * 8];
#pragma unroll
            for (int jj = 0; jj < 4; ++jj)
                bfr[jj] = *(const bf16x8*)&Bs[(wn * 64 + jj * 16 + col) * 72 + kk * 32 + kg * 8];
#pragma unroll
            for (int i = 0; i < 4; ++i)
#pragma unroll
                for (int jj = 0; jj < 4; ++jj)
                    acc[i][jj] = __builtin_amdgcn_mfma_f32_16x16x32_bf16(af[i], bfr[jj], acc[i][jj], 0, 0, 0);
        }
    }

    // partial store: frag layout, fully coalesced float4
    float* pout = ws + WS_PART + ((long)(j * 32 + c) * 256 + tid) * 64;
#pragma unroll
    for (int i = 0; i < 4; ++i)
#pragma unroll
        for (int jj = 0; jj < 4; ++jj)
            *(f32x4*)(pout + (i * 4 + jj) * 4) = acc[i][jj];

    if (doVS) {
#pragma unroll
        for (int m = 32; m; m >>= 1) vs += __shfl_xor(vs, m);
        if (lane == 0) atomicAdd(&ws[WS_VSQ], vs);
    }
    if (doCS) {
        __syncthreads();
        float* cred = (float*)sm;
        cred[bcol * 4 + wv] = cs0;
        cred[(bcol + 1) * 4 + wv] = cs1;
        __syncthreads();
        if (tid < 128) {
            float s = cred[tid * 4] + cred[tid * 4 + 1] + cred[tid * 4 + 2] + cred[tid * 4 + 3];
            atomicAdd(&ws[WS_COLSUM + ct * 128 + tid], s);
        }
    }
}

// =====================================================================
// K1': retrieved = k @ W.T.  2048 blocks; rowtile = bx&511 so the 4
// blocks sharing a k-slab are bx {r, r+512, ...} -> same XCD (bx%8).
// Register double-buffer prefetch of A and B. Lean scalar epilogue.
// =====================================================================
__global__ __launch_bounds__(256, 3)
void k1_retr(const float* __restrict__ kmat, const float* __restrict__ Wmat,
             float* __restrict__ out) {
    __shared__ u16 sm[18432];
    const int tid = threadIdx.x;
    const int bx = blockIdx.x;
    const int rowtile = bx & 511, nt = bx >> 9;
    const long b0 = (long)rowtile * 128;
    const int vd0 = nt * 128;
    const int wv = tid >> 6, lane = tid & 63;
    const int wm = wv & 1, wn = wv >> 1;
    const int col = lane & 15, kg = lane >> 4;
    const int srow = tid >> 4, scol = (tid & 15) * 4;

    f32x4 acc[4][4] = {};
    const float* gA0 = kmat + (b0 + srow) * 512 + scol;
    const float* gB0 = Wmat + (long)(vd0 + srow) * 512 + scol;

    float4 aR[8], bR[8];
#pragma unroll
    for (int i = 0; i < 8; ++i) {
        aR[i] = *(const float4*)(gA0 + (long)i * 16 * 512);
        bR[i] = *(const float4*)(gB0 + (long)i * 16 * 512);
    }

    for (int it = 0; it < 8; ++it) {
        __syncthreads();
#pragma unroll
        for (int i = 0; i < 8; ++i) {
            int r = i * 16 + srow;
            *(uint2*)&sm[r * 72 + scol] = make_uint2(pkbf2(aR[i].x, aR[i].y), pkbf2(aR[i].z, aR[i].w));
            *(uint2*)&sm[9216 + r * 72 + scol] = make_uint2(pkbf2(bR[i].x, bR[i].y), pkbf2(bR[i].z, bR[i].w));
        }
        __syncthreads();
        if (it < 7) {
            const float* ga = gA0 + (it + 1) * 64;
            const float* gb = gB0 + (it + 1) * 64;
#pragma unroll
            for (int i = 0; i < 8; ++i) {
                aR[i] = *(const float4*)(ga + (long)i * 16 * 512);
                bR[i] = *(const float4*)(gb + (long)i * 16 * 512);
            }
        }
#pragma unroll
        for (int kk = 0; kk < 2; ++kk) {
            bf16x8 af[4], bfr[4];
#pragma unroll
            for (int i = 0; i < 4; ++i)
                af[i] = *(const bf16x8*)&sm[(wm * 64 + i * 16 + col) * 72 + kk * 32 + kg * 8];
#pragma unroll
            for (int jj = 0; jj < 4; ++jj)
                bfr[jj] = *(const bf16x8*)&sm[9216 + (wn * 64 + jj * 16 + col) * 72 + kk * 32 + kg * 8];
#pragma unroll
            for (int i = 0; i < 4; ++i)
#pragma unroll
                for (int jj = 0; jj < 4; ++jj)
                    acc[i][jj] = __builtin_amdgcn_mfma_f32_16x16x32_bf16(af[i], bfr[jj], acc[i][jj], 0, 0, 0);
        }
    }

    const int rg = lane >> 4;
#pragma unroll
    for (int i = 0; i < 4; ++i)
#pragma unroll
        for (int jj = 0; jj < 4; ++jj) {
            int r0 = wm * 64 + i * 16 + rg * 4;
            int cc = wn * 64 + jj * 16 + col;
            long gb = b0 + r0;
#pragma unroll
            for (int r = 0; r < 4; ++r)
                out[(gb + r) * 512 + vd0 + cc] = acc[i][jj][r];
        }
}

// =====================================================================
// K2r: reduce partials over 32 chunks -> compact G1 (with symmetry
// mirror) and G2. Block 0 also computes the gates from colsum.
// 416 blocks x 256 (26 jobs x 4096 threads).
// =====================================================================
__global__ __launch_bounds__(256)
void k2_reduce(float* __restrict__ ws, const float* __restrict__ gw,
               const float* __restrict__ gb) {
    const int g = blockIdx.x * 256 + threadIdx.x;
    const int j = g >> 12;
    const int s = g & 4095;
    const int tp = s >> 4;      // source tid
    const int grp = s & 15;     // float4 index within the thread's 64

    f32x4 sum = {};
    const float* pbase = ws + WS_PART + ((long)j * 8192 + tp) * 64 + grp * 4;
#pragma unroll 8
    for (int c = 0; c < 32; ++c)
        sum += *(const f32x4*)(pbase + (long)c * 16384);

    const int wm = (tp >> 6) & 1, wn = tp >> 7;
    const int l = tp & 63, rg = l >> 4, cl = l & 15;
    const int i = grp >> 2, jj = grp & 3;
    const int m0 = wm * 64 + i * 16 + rg * 4;
    const int n = wn * 64 + jj * 16 + cl;

    int isG2, rt, ct;
    jobdec(j, isG2, rt, ct);
    const int r0 = rt * 128, c0 = ct * 128;
    if (!isG2) {
#pragma unroll
        for (int q = 0; q < 4; ++q) {
            float val = sum[q];
            ws[WS_G1 + (r0 + m0 + q) * 512 + c0 + n] = val;
            if (rt != ct) ws[WS_G1 + (c0 + n) * 512 + r0 + m0 + q] = val;
        }
    } else {
#pragma unroll
        for (int q = 0; q < 4; ++q)
            ws[WS_G2 + (r0 + m0 + q) * 512 + c0 + n] = sum[q];
    }

    if (blockIdx.x == 0 && threadIdx.x < 64) {
        const int t = threadIdx.x;
        float d0 = 0.f, d1 = 0.f, d2 = 0.f;
#pragma unroll
        for (int ii = 0; ii < 8; ++ii) {
            int kd = ii * 64 + t;
            float km = ws[WS_COLSUM + kd] * (1.0f / 65536.0f);
            d0 += gw[kd] * km;
            d1 += gw[512 + kd] * km;
            d2 += gw[1024 + kd] * km;
        }
#pragma unroll
        for (int m = 32; m; m >>= 1) {
            d0 += __shfl_xor(d0, m);
            d1 += __shfl_xor(d1, m);
            d2 += __shfl_xor(d2, m);
        }
        if (t == 0) {
            ws[WS_GATES + 0] = 1.f / (1.f + __expf(-(d0 + gb[0])));   // alpha
            ws[WS_GATES + 1] = 1.f / (1.f + __expf(-(d1 + gb[1])));   // eta
            ws[WS_GATES + 2] = 1.f / (1.f + __expf(-(d2 + gb[2])));   // theta
        }
    }
}

// =====================================================================
// K3a: WG1 = W @ G1 (fp32 vector), grad = c*(WG1 - G2), new_S/new_W,
// trace dots for the loss. 256 blocks x 256 (one float4 per thread).
// =====================================================================
__global__ __launch_bounds__(256)
void k3_main(const float* __restrict__ Wmat, const float* __restrict__ Smat,
             float* __restrict__ ws, float* __restrict__ out) {
    const int g = blockIdx.x * 256 + threadIdx.x;
    const int m = g >> 7;              // wave-uniform
    const int n0 = (g & 127) * 4;
    const float* wrow = Wmat + m * 512;

    f32x4 acc = {};
    for (int jx = 0; jx < 512; jx += 4) {
#pragma unroll
        for (int t = 0; t < 4; ++t) {
            float wsc = wrow[jx + t];
            f32x4 g1 = *(const f32x4*)(ws + WS_G1 + (jx + t) * 512 + n0);
            acc += g1 * wsc;
        }
    }
    f32x4 g2 = *(const f32x4*)(ws + WS_G2 + m * 512 + n0);
    f32x4 w4 = *(const f32x4*)(Wmat + m * 512 + n0);
    f32x4 s4 = *(const f32x4*)(Smat + m * 512 + n0);
    const float alpha = ws[WS_GATES], eta = ws[WS_GATES + 1], theta = ws[WS_GATES + 2];
    const float c1 = 5.9604644775390625e-8f;    // 2/(B*VD)

    f32x4 grad = (acc - g2) * c1;
    f32x4 ns = s4 * eta - grad * theta;
    f32x4 nw = w4 * (1.f - alpha) + ns;
    const int base = m * 512 + n0;
#pragma unroll
    for (int q = 0; q < 4; ++q) {        // OUT_W/OUT_S bases are odd -> scalar stores
        out[OUT_S + base + q] = ns[q];
        out[OUT_W + base + q] = nw[q];
    }

    float t1 = acc[0] * w4[0] + acc[1] * w4[1] + acc[2] * w4[2] + acc[3] * w4[3];
    float t2 = g2[0] * w4[0] + g2[1] * w4[1] + g2[2] * w4[2] + g2[3] * w4[3];
#pragma unroll
    for (int mm = 32; mm; mm >>= 1) {
        t1 += __shfl_xor(t1, mm);
        t2 += __shfl_xor(t2, mm);
    }
    if ((threadIdx.x & 63) == 0) {
        atomicAdd(&ws[WS_TR1], t1);
        atomicAdd(&ws[WS_TR2], t2);
    }
}

__global__ void k3_loss(const float* __restrict__ ws, float* __restrict__ out) {
    out[OUT_LOSS] = (ws[WS_TR1] - 2.f * ws[WS_TR2] + ws[WS_VSQ]) * 2.98023223876953125e-8f;
}

extern "C" void kernel_launch(void* const* d_in, const int* in_sizes, int n_in,
                              void* d_out, int out_size, void* d_ws, size_t ws_size,
                              hipStream_t stream) {
    const float* k  = (const float*)d_in[0];
    const float* v  = (const float*)d_in[1];
    const float* W  = (const float*)d_in[2];
    const float* S  = (const float*)d_in[3];
    const float* gw = (const float*)d_in[4];
    const float* gb = (const float*)d_in[5];
    float* out = (float*)d_out;
    float* ws  = (float*)d_ws;

    // zero colsum/vsq/gates/traces (518 floats from WS_COLSUM)
    hipMemsetAsync((char*)d_ws + (size_t)WS_COLSUM * 4, 0, 518 * 4, stream);

    hipLaunchKernelGGL(kg_gram,   dim3(832),  dim3(256), 0, stream, k, v, ws);
    hipLaunchKernelGGL(k1_retr,   dim3(2048), dim3(256), 0, stream, k, W, out);
    hipLaunchKernelGGL(k2_reduce, dim3(416),  dim3(256), 0, stream, ws, gw, gb);
    hipLaunchKernelGGL(k3_main,   dim3(256),  dim3(256), 0, stream, W, S, ws, out);
    hipLaunchKernelGGL(k3_loss,   dim3(1),    dim3(1),   0, stream, ws, out);
}